// Round 1
// baseline (3082.129 us; speedup 1.0000x reference)
//
#include <hip/hip_runtime.h>
#include <cmath>

// Problem constants (from reference): B=32, S=2048, E=1024, D=1024
constexpr int B_ = 32;
constexpr int S_ = 2048;
constexpr int E_ = 1024;
constexpr int D_ = 1024;
constexpr int M_ = S_ * B_;   // 65536 flattened (s,b) rows of encoder_outputs

// ---------------------------------------------------------------------------
// K1: dec_proj[b,d] = sum_k hidden[b,k] * Wd[d,k]     (hidden @ Wd^T)
// 32768 outputs, each a 1024-dot. Tiny kernel; float4 vectorized.
// ---------------------------------------------------------------------------
__global__ __launch_bounds__(256) void dec_proj_kernel(
    const float* __restrict__ hidden,  // [B, D]
    const float* __restrict__ Wd,      // [D, D]
    float* __restrict__ dec)           // [B, D]
{
    int idx = blockIdx.x * blockDim.x + threadIdx.x;   // b*D + d
    int b = idx >> 10;
    int d = idx & (D_ - 1);
    const float4* h4 = reinterpret_cast<const float4*>(hidden + (size_t)b * D_);
    const float4* w4 = reinterpret_cast<const float4*>(Wd + (size_t)d * D_);
    float acc = 0.f;
#pragma unroll 4
    for (int k = 0; k < D_ / 4; ++k) {
        float4 h = h4[k], w = w4[k];
        acc += h.x * w.x + h.y * w.y + h.z * w.z + h.w * w.w;
    }
    dec[idx] = acc;
}

// ---------------------------------------------------------------------------
// K2: fused  C[m,n] = sum_k enc[m,k]*We[n,k]  ->  tanh(C + dec)  ->  dot(v)
// scores[m] += sum_{n in tile} v[n] * tanh(C[m,n] + dec[b(m),n]),  b(m)=m&31
// 64x64 tile, BK=16, 256 threads, 4x4 per thread. Never materializes energy.
// ---------------------------------------------------------------------------
constexpr int BM = 64, BN = 64, BK = 16;

__global__ __launch_bounds__(256) void score_gemm_kernel(
    const float* __restrict__ enc,    // [M, E]  (row m = s*B + b)
    const float* __restrict__ We,     // [D, E]
    const float* __restrict__ dec,    // [B, D]
    const float* __restrict__ v,      // [D]
    float* __restrict__ scores)       // [M], pre-zeroed, atomic accumulate
{
    __shared__ float As[BM][BK + 1];
    __shared__ float Bs[BN][BK + 1];
    __shared__ float red[BM][17];

    const int m0 = blockIdx.x * BM;
    const int n0 = blockIdx.y * BN;
    const int t  = threadIdx.x;
    const int tx = t & 15;        // 0..15 -> n micro
    const int ty = t >> 4;        // 0..15 -> m micro

    // global->LDS load mapping: thread t loads float4 at (row = t/4, col = (t%4)*4)
    const int lrow = t >> 2;
    const int lcol = (t & 3) * 4;

    float acc[4][4] = {};

    for (int k0 = 0; k0 < E_; k0 += BK) {
        float4 a = *reinterpret_cast<const float4*>(
            enc + (size_t)(m0 + lrow) * E_ + k0 + lcol);
        float4 w = *reinterpret_cast<const float4*>(
            We + (size_t)(n0 + lrow) * E_ + k0 + lcol);
        As[lrow][lcol + 0] = a.x; As[lrow][lcol + 1] = a.y;
        As[lrow][lcol + 2] = a.z; As[lrow][lcol + 3] = a.w;
        Bs[lrow][lcol + 0] = w.x; Bs[lrow][lcol + 1] = w.y;
        Bs[lrow][lcol + 2] = w.z; Bs[lrow][lcol + 3] = w.w;
        __syncthreads();

#pragma unroll
        for (int kk = 0; kk < BK; ++kk) {
            float av[4], bw[4];
#pragma unroll
            for (int i = 0; i < 4; ++i) av[i] = As[ty * 4 + i][kk];
#pragma unroll
            for (int j = 0; j < 4; ++j) bw[j] = Bs[tx * 4 + j][kk];
#pragma unroll
            for (int i = 0; i < 4; ++i)
#pragma unroll
                for (int j = 0; j < 4; ++j)
                    acc[i][j] += av[i] * bw[j];
        }
        __syncthreads();
    }

    // fused epilogue: partial score per row
    float p[4];
#pragma unroll
    for (int i = 0; i < 4; ++i) {
        int m = m0 + ty * 4 + i;
        int b = m & (B_ - 1);
        float s = 0.f;
#pragma unroll
        for (int j = 0; j < 4; ++j) {
            int n = n0 + tx * 4 + j;
            s += v[n] * tanhf(acc[i][j] + dec[b * D_ + n]);
        }
        p[i] = s;
    }
#pragma unroll
    for (int i = 0; i < 4; ++i) red[ty * 4 + i][tx] = p[i];
    __syncthreads();
    if (t < BM) {
        float s = 0.f;
#pragma unroll
        for (int j = 0; j < 16; ++j) s += red[t][j];
        atomicAdd(&scores[m0 + t], s);
    }
}

// ---------------------------------------------------------------------------
// K3: softmax over s (per batch b). scores indexed [s*B+b]; attn out [b*S+s].
// ---------------------------------------------------------------------------
__global__ __launch_bounds__(256) void softmax_kernel(
    const float* __restrict__ scores,  // [M], m = s*B+b
    float* __restrict__ attn)          // [B, S]
{
    const int b = blockIdx.x;
    const int t = threadIdx.x;
    __shared__ float sm[256];

    float vals[8];
    float lmax = -INFINITY;
#pragma unroll
    for (int i = 0; i < 8; ++i) {
        int s = t + i * 256;
        vals[i] = scores[s * B_ + b];
        lmax = fmaxf(lmax, vals[i]);
    }
    sm[t] = lmax; __syncthreads();
    for (int off = 128; off > 0; off >>= 1) {
        if (t < off) sm[t] = fmaxf(sm[t], sm[t + off]);
        __syncthreads();
    }
    const float mx = sm[0];
    __syncthreads();

    float lsum = 0.f;
#pragma unroll
    for (int i = 0; i < 8; ++i) {
        vals[i] = expf(vals[i] - mx);
        lsum += vals[i];
    }
    sm[t] = lsum; __syncthreads();
    for (int off = 128; off > 0; off >>= 1) {
        if (t < off) sm[t] += sm[t + off];
        __syncthreads();
    }
    const float inv = 1.f / sm[0];
#pragma unroll
    for (int i = 0; i < 8; ++i)
        attn[b * S_ + t + i * 256] = vals[i] * inv;
}

// ---------------------------------------------------------------------------
// K4: context[b,e] = sum_s attn[b,s] * enc[s,b,e]
// grid: (b, e-chunk of 256, s-chunk of 256); atomic accumulate per element.
// ---------------------------------------------------------------------------
__global__ __launch_bounds__(256) void context_kernel(
    const float* __restrict__ enc,   // [S, B, E]
    const float* __restrict__ attn,  // [B, S]
    float* __restrict__ ctx)         // [B, E], pre-zeroed
{
    const int e0 = (blockIdx.x & 3) * 256;          // 4 e-chunks
    const int b  = (blockIdx.x >> 2) & (B_ - 1);    // 32 batches
    const int sc = blockIdx.x >> 7;                 // 8 s-chunks
    const int e  = e0 + threadIdx.x;

    float acc = 0.f;
    const int s_end = sc * 256 + 256;
    for (int s = sc * 256; s < s_end; ++s) {
        acc += attn[b * S_ + s] * enc[((size_t)s * B_ + b) * E_ + e];
    }
    atomicAdd(&ctx[b * E_ + e], acc);
}

// ---------------------------------------------------------------------------
extern "C" void kernel_launch(void* const* d_in, const int* in_sizes, int n_in,
                              void* d_out, int out_size, void* d_ws, size_t ws_size,
                              hipStream_t stream) {
    const float* hidden = (const float*)d_in[0];  // [B, D]
    const float* enc    = (const float*)d_in[1];  // [S, B, E]
    const float* We     = (const float*)d_in[2];  // [D, E]
    const float* Wd     = (const float*)d_in[3];  // [D, D]
    const float* v      = (const float*)d_in[4];  // [D]

    float* ctx  = (float*)d_out;                  // [B, E]
    float* attn = (float*)d_out + B_ * E_;        // [B, S]

    float* dec    = (float*)d_ws;                 // [B, D]   32768 floats
    float* scores = (float*)d_ws + B_ * D_;       // [M]      65536 floats

    // zero accumulated buffers (ws/out are poisoned 0xAA before every launch)
    hipMemsetAsync(scores, 0, (size_t)M_ * sizeof(float), stream);
    hipMemsetAsync(ctx, 0, (size_t)B_ * E_ * sizeof(float), stream);

    // K1: dec_proj
    dec_proj_kernel<<<(B_ * D_) / 256, 256, 0, stream>>>(hidden, Wd, dec);

    // K2: fused score GEMM (M=65536 x N=1024, K=1024)
    dim3 g2(M_ / BM, D_ / BN);   // (1024, 16)
    score_gemm_kernel<<<g2, 256, 0, stream>>>(enc, We, dec, v, scores);

    // K3: softmax over s per batch
    softmax_kernel<<<B_, 256, 0, stream>>>(scores, attn);

    // K4: context
    context_kernel<<<B_ * 4 * 8, 256, 0, stream>>>(enc, attn, ctx);
}

// Round 2
// 724.106 us; speedup vs baseline: 4.2565x; 4.2565x over previous
//
#include <hip/hip_runtime.h>
#include <cmath>
#include <cstdint>

// Problem constants: B=32, S=2048, E=1024, D=1024
constexpr int B_ = 32;
constexpr int S_ = 2048;
constexpr int E_ = 1024;
constexpr int D_ = 1024;
constexpr int K_ = E_;        // GEMM K
constexpr int M_ = S_ * B_;   // 65536 rows (m = s*B + b)

typedef float f32x4 __attribute__((ext_vector_type(4)));
typedef __bf16 bf16x8 __attribute__((ext_vector_type(8)));

// ---------------------------------------------------------------------------
// K1: dec_proj[b,d] = sum_k hidden[b,k] * Wd[d,k]   (fp32, tiny)
// ---------------------------------------------------------------------------
__global__ __launch_bounds__(256) void dec_proj_kernel(
    const float* __restrict__ hidden,  // [B, D]
    const float* __restrict__ Wd,      // [D, D]
    float* __restrict__ dec)           // [B, D]
{
    int idx = blockIdx.x * blockDim.x + threadIdx.x;
    int b = idx >> 10;
    int d = idx & (D_ - 1);
    const float4* h4 = reinterpret_cast<const float4*>(hidden + (size_t)b * D_);
    const float4* w4 = reinterpret_cast<const float4*>(Wd + (size_t)d * D_);
    float acc = 0.f;
#pragma unroll 4
    for (int k = 0; k < D_ / 4; ++k) {
        float4 h = h4[k], w = w4[k];
        acc += h.x * w.x + h.y * w.y + h.z * w.z + h.w * w.w;
    }
    dec[idx] = acc;
}

// ---------------------------------------------------------------------------
// K0: fp32 -> bf16 (RNE) bulk convert, 4 elements/thread
// ---------------------------------------------------------------------------
__device__ __forceinline__ uint16_t f2bf(float f) {
    uint32_t u = __float_as_uint(f);
    u += 0x7FFFu + ((u >> 16) & 1u);
    return (uint16_t)(u >> 16);
}

__global__ __launch_bounds__(256) void f32_to_bf16_kernel(
    const float* __restrict__ in, uint16_t* __restrict__ out, int n4)
{
    int i = blockIdx.x * 256 + threadIdx.x;
    if (i >= n4) return;
    float4 v = reinterpret_cast<const float4*>(in)[i];
    ushort4 o;
    o.x = f2bf(v.x); o.y = f2bf(v.y); o.z = f2bf(v.z); o.w = f2bf(v.w);
    reinterpret_cast<ushort4*>(out)[i] = o;
}

// ---------------------------------------------------------------------------
// K2 (fast path): MFMA bf16 GEMM fused with tanh + v-dot -> scores
//   C[m,n] = sum_k A[m,k]*Bw[n,k]  (NT; both operands K-major)
//   scores[m] += sum_n v[n]*tanh(C[m,n] + dec[m&31, n])
// 128x128 tile, BK=32, 256 threads = 4 waves, each wave 64x64 via 4x4
// mfma_f32_16x16x32_bf16. global_load_lds width-16 staging (m97 structure).
// ---------------------------------------------------------------------------
constexpr int TM = 128, TN = 128, TK = 32;

__global__ __launch_bounds__(256) void score_mfma_kernel(
    const uint16_t* __restrict__ A,   // enc bf16 [M, K]
    const uint16_t* __restrict__ Bw,  // We  bf16 [D, K]
    const float* __restrict__ dec,    // [B, D]
    const float* __restrict__ v,      // [D]
    float* __restrict__ scores)       // [M], pre-zeroed, atomic accumulate
{
    __shared__ __align__(16) uint16_t As[TM * TK];  // 8 KB, row-major [128][32]
    __shared__ __align__(16) uint16_t Bs[TN * TK];  // 8 KB

    const int nb = blockIdx.x & 7;    // n fast: blocks sharing an A-tile adjacent
    const int mb = blockIdx.x >> 3;
    const int m0 = mb * TM;
    const int n0 = nb * TN;

    const int t    = threadIdx.x;
    const int wave = t >> 6;          // 0..3
    const int lane = t & 63;
    const int wm   = (wave & 1) * 64; // wave's 64x64 quadrant
    const int wn   = (wave >> 1) * 64;
    const int q    = lane >> 4;       // 0..3
    const int r16  = lane & 15;

    // staging: chunk c = wave*2+i covers rows c*16..c*16+16 (1024 B each)
    const int srow = lane >> 2;           // row within chunk
    const int scol = (lane & 3) * 8;      // u16 offset within row (16 B)

    f32x4 acc[4][4] = {};

    for (int k0 = 0; k0 < K_; k0 += TK) {
        __syncthreads();
#pragma unroll
        for (int i = 0; i < 2; ++i) {
            const int c = wave * 2 + i;
            const uint16_t* ga = A + (size_t)(m0 + c * 16 + srow) * K_ + k0 + scol;
            __builtin_amdgcn_global_load_lds(
                (const __attribute__((address_space(1))) uint32_t*)ga,
                (__attribute__((address_space(3))) uint32_t*)(As + c * 512),
                16, 0, 0);
            const uint16_t* gb = Bw + (size_t)(n0 + c * 16 + srow) * K_ + k0 + scol;
            __builtin_amdgcn_global_load_lds(
                (const __attribute__((address_space(1))) uint32_t*)gb,
                (__attribute__((address_space(3))) uint32_t*)(Bs + c * 512),
                16, 0, 0);
        }
        __syncthreads();

        bf16x8 af[4], bf[4];
#pragma unroll
        for (int i = 0; i < 4; ++i) {
            af[i] = __builtin_bit_cast(bf16x8,
                *reinterpret_cast<const int4*>(As + (wm + i * 16 + r16) * TK + q * 8));
            bf[i] = __builtin_bit_cast(bf16x8,
                *reinterpret_cast<const int4*>(Bs + (wn + i * 16 + r16) * TK + q * 8));
        }
#pragma unroll
        for (int i = 0; i < 4; ++i)
#pragma unroll
            for (int j = 0; j < 4; ++j)
                acc[i][j] = __builtin_amdgcn_mfma_f32_16x16x32_bf16(
                    af[i], bf[j], acc[i][j], 0, 0, 0);
    }

    // fused epilogue: C/D layout col = lane&15, row = q*4 + reg
#pragma unroll
    for (int i = 0; i < 4; ++i) {
#pragma unroll
        for (int r = 0; r < 4; ++r) {
            const int m = m0 + wm + i * 16 + q * 4 + r;
            const int b = m & (B_ - 1);
            float p = 0.f;
#pragma unroll
            for (int j = 0; j < 4; ++j) {
                const int n = n0 + wn + j * 16 + r16;
                p += v[n] * tanhf(acc[i][j][r] + dec[b * D_ + n]);
            }
            p += __shfl_xor(p, 1);
            p += __shfl_xor(p, 2);
            p += __shfl_xor(p, 4);
            p += __shfl_xor(p, 8);
            if (r16 == 0) atomicAdd(&scores[m], p);
        }
    }
}

// ---------------------------------------------------------------------------
// K2 (fallback path, fp32): round-1 kernel, used only if ws too small
// ---------------------------------------------------------------------------
constexpr int BM = 64, BN = 64, BK = 16;

__global__ __launch_bounds__(256) void score_gemm_kernel(
    const float* __restrict__ enc, const float* __restrict__ We,
    const float* __restrict__ dec, const float* __restrict__ v,
    float* __restrict__ scores)
{
    __shared__ float As[BM][BK + 1];
    __shared__ float Bs[BN][BK + 1];
    __shared__ float red[BM][17];

    const int m0 = blockIdx.x * BM;
    const int n0 = blockIdx.y * BN;
    const int t  = threadIdx.x;
    const int tx = t & 15;
    const int ty = t >> 4;
    const int lrow = t >> 2;
    const int lcol = (t & 3) * 4;

    float acc[4][4] = {};
    for (int k0 = 0; k0 < E_; k0 += BK) {
        float4 a = *reinterpret_cast<const float4*>(enc + (size_t)(m0 + lrow) * E_ + k0 + lcol);
        float4 w = *reinterpret_cast<const float4*>(We + (size_t)(n0 + lrow) * E_ + k0 + lcol);
        As[lrow][lcol + 0] = a.x; As[lrow][lcol + 1] = a.y;
        As[lrow][lcol + 2] = a.z; As[lrow][lcol + 3] = a.w;
        Bs[lrow][lcol + 0] = w.x; Bs[lrow][lcol + 1] = w.y;
        Bs[lrow][lcol + 2] = w.z; Bs[lrow][lcol + 3] = w.w;
        __syncthreads();
#pragma unroll
        for (int kk = 0; kk < BK; ++kk) {
            float av[4], bw[4];
#pragma unroll
            for (int i = 0; i < 4; ++i) av[i] = As[ty * 4 + i][kk];
#pragma unroll
            for (int j = 0; j < 4; ++j) bw[j] = Bs[tx * 4 + j][kk];
#pragma unroll
            for (int i = 0; i < 4; ++i)
#pragma unroll
                for (int j = 0; j < 4; ++j)
                    acc[i][j] += av[i] * bw[j];
        }
        __syncthreads();
    }
    float p[4];
#pragma unroll
    for (int i = 0; i < 4; ++i) {
        int m = m0 + ty * 4 + i;
        int b = m & (B_ - 1);
        float s = 0.f;
#pragma unroll
        for (int j = 0; j < 4; ++j) {
            int n = n0 + tx * 4 + j;
            s += v[n] * tanhf(acc[i][j] + dec[b * D_ + n]);
        }
        p[i] = s;
    }
#pragma unroll
    for (int i = 0; i < 4; ++i) red[ty * 4 + i][tx] = p[i];
    __syncthreads();
    if (t < BM) {
        float s = 0.f;
#pragma unroll
        for (int j = 0; j < 16; ++j) s += red[t][j];
        atomicAdd(&scores[m0 + t], s);
    }
}

// ---------------------------------------------------------------------------
// K3: softmax over s per batch. scores[m = s*B+b] -> attn[b*S+s]
// ---------------------------------------------------------------------------
__global__ __launch_bounds__(256) void softmax_kernel(
    const float* __restrict__ scores, float* __restrict__ attn)
{
    const int b = blockIdx.x;
    const int t = threadIdx.x;
    __shared__ float sm[256];

    float vals[8];
    float lmax = -INFINITY;
#pragma unroll
    for (int i = 0; i < 8; ++i) {
        int s = t + i * 256;
        vals[i] = scores[s * B_ + b];
        lmax = fmaxf(lmax, vals[i]);
    }
    sm[t] = lmax; __syncthreads();
    for (int off = 128; off > 0; off >>= 1) {
        if (t < off) sm[t] = fmaxf(sm[t], sm[t + off]);
        __syncthreads();
    }
    const float mx = sm[0];
    __syncthreads();

    float lsum = 0.f;
#pragma unroll
    for (int i = 0; i < 8; ++i) {
        vals[i] = expf(vals[i] - mx);
        lsum += vals[i];
    }
    sm[t] = lsum; __syncthreads();
    for (int off = 128; off > 0; off >>= 1) {
        if (t < off) sm[t] += sm[t + off];
        __syncthreads();
    }
    const float inv = 1.f / sm[0];
#pragma unroll
    for (int i = 0; i < 8; ++i)
        attn[b * S_ + t + i * 256] = vals[i] * inv;
}

// ---------------------------------------------------------------------------
// K4 (fast): context[b,e] = sum_s attn[b,s] * enc_bf16[s,b,e]
// 256 blocks = 32 b x 8 s-chunks; thread covers 4 e (one 8B load per s).
// ---------------------------------------------------------------------------
__global__ __launch_bounds__(256) void context_bf16_kernel(
    const uint16_t* __restrict__ encb,  // [S, B, E] bf16
    const float* __restrict__ attn,     // [B, S]
    float* __restrict__ ctx)            // [B, E], pre-zeroed
{
    const int b  = blockIdx.x & (B_ - 1);
    const int sc = blockIdx.x >> 5;     // 0..7
    const int e0 = threadIdx.x * 4;

    float a0 = 0.f, a1 = 0.f, a2 = 0.f, a3 = 0.f;
    const int s_end = sc * 256 + 256;
    for (int s = sc * 256; s < s_end; ++s) {
        const float w = attn[b * S_ + s];
        uint2 u = *reinterpret_cast<const uint2*>(
            encb + ((size_t)s * B_ + b) * E_ + e0);
        a0 += w * __uint_as_float((u.x & 0xFFFFu) << 16);
        a1 += w * __uint_as_float((u.x & 0xFFFF0000u));
        a2 += w * __uint_as_float((u.y & 0xFFFFu) << 16);
        a3 += w * __uint_as_float((u.y & 0xFFFF0000u));
    }
    atomicAdd(&ctx[b * E_ + e0 + 0], a0);
    atomicAdd(&ctx[b * E_ + e0 + 1], a1);
    atomicAdd(&ctx[b * E_ + e0 + 2], a2);
    atomicAdd(&ctx[b * E_ + e0 + 3], a3);
}

// K4 (fallback, fp32)
__global__ __launch_bounds__(256) void context_kernel(
    const float* __restrict__ enc, const float* __restrict__ attn,
    float* __restrict__ ctx)
{
    const int e0 = (blockIdx.x & 3) * 256;
    const int b  = (blockIdx.x >> 2) & (B_ - 1);
    const int sc = blockIdx.x >> 7;
    const int e  = e0 + threadIdx.x;
    float acc = 0.f;
    const int s_end = sc * 256 + 256;
    for (int s = sc * 256; s < s_end; ++s)
        acc += attn[b * S_ + s] * enc[((size_t)s * B_ + b) * E_ + e];
    atomicAdd(&ctx[b * E_ + e], acc);
}

// ---------------------------------------------------------------------------
extern "C" void kernel_launch(void* const* d_in, const int* in_sizes, int n_in,
                              void* d_out, int out_size, void* d_ws, size_t ws_size,
                              hipStream_t stream) {
    const float* hidden = (const float*)d_in[0];  // [B, D]
    const float* enc    = (const float*)d_in[1];  // [S, B, E]
    const float* We     = (const float*)d_in[2];  // [D, E]
    const float* Wd     = (const float*)d_in[3];  // [D, D]
    const float* v      = (const float*)d_in[4];  // [D]

    float* ctx  = (float*)d_out;                  // [B, E]
    float* attn = (float*)d_out + B_ * E_;        // [B, S]

    float*    dec    = (float*)d_ws;              // [B*D]
    float*    scores = dec + B_ * D_;             // [M]
    uint16_t* Web    = (uint16_t*)(scores + M_);  // [D*K]
    uint16_t* encb   = Web + (size_t)D_ * K_;     // [M*K]

    const size_t need = (size_t)(B_ * D_ + M_) * 4
                      + ((size_t)D_ * K_ + (size_t)M_ * K_) * 2;
    const bool fast = ws_size >= need;

    hipMemsetAsync(scores, 0, (size_t)M_ * sizeof(float), stream);
    hipMemsetAsync(ctx, 0, (size_t)B_ * E_ * sizeof(float), stream);

    dec_proj_kernel<<<(B_ * D_) / 256, 256, 0, stream>>>(hidden, Wd, dec);

    if (fast) {
        f32_to_bf16_kernel<<<(D_ * K_ / 4) / 256, 256, 0, stream>>>(
            We, Web, D_ * K_ / 4);
        const int enc_n4 = M_ * K_ / 4;  // 16,777,216
        f32_to_bf16_kernel<<<enc_n4 / 256, 256, 0, stream>>>(enc, encb, enc_n4);

        score_mfma_kernel<<<(M_ / TM) * (D_ / TN), 256, 0, stream>>>(
            encb, Web, dec, v, scores);

        softmax_kernel<<<B_, 256, 0, stream>>>(scores, attn);
        context_bf16_kernel<<<B_ * 8, 256, 0, stream>>>(encb, attn, ctx);
    } else {
        dim3 g2(M_ / BM, D_ / BN);
        score_gemm_kernel<<<g2, 256, 0, stream>>>(enc, We, dec, v, scores);
        softmax_kernel<<<B_, 256, 0, stream>>>(scores, attn);
        context_kernel<<<B_ * 4 * 8, 256, 0, stream>>>(enc, attn, ctx);
    }
}

// Round 3
// 690.974 us; speedup vs baseline: 4.4606x; 1.0479x over previous
//
#include <hip/hip_runtime.h>
#include <cmath>
#include <cstdint>

// Problem constants: B=32, S=2048, E=1024, D=1024
constexpr int B_ = 32;
constexpr int S_ = 2048;
constexpr int E_ = 1024;
constexpr int D_ = 1024;
constexpr int K_ = E_;        // GEMM K
constexpr int M_ = S_ * B_;   // 65536 rows (m = s*B + b)
constexpr int SC_ = 32;       // context s-chunks

typedef float f32x4 __attribute__((ext_vector_type(4)));
typedef __bf16 bf16x8 __attribute__((ext_vector_type(8)));

// fast tanh: 1 - 2/(exp(2x)+1), saturates correctly at +/-inf. ~6 VALU ops.
__device__ __forceinline__ float fast_tanh(float x) {
    float e = __builtin_amdgcn_exp2f(x * 2.88539008177793f);  // exp(2x)
    return 1.f - 2.f * __builtin_amdgcn_rcpf(e + 1.f);
}

// ---------------------------------------------------------------------------
// K1: dec_proj[b,d] = sum_k hidden[b,k]*Wd[d,k]. One wave per output.
// ---------------------------------------------------------------------------
__global__ __launch_bounds__(256) void dec_proj_wave_kernel(
    const float* __restrict__ hidden,  // [B, D]
    const float* __restrict__ Wd,      // [D, D]
    float* __restrict__ dec)           // [B, D]
{
    const int o = blockIdx.x * 4 + (threadIdx.x >> 6);  // output index b*D+d
    const int lane = threadIdx.x & 63;
    const int b = o >> 10;
    const int d = o & (D_ - 1);
    const float4* h4 = reinterpret_cast<const float4*>(hidden + (size_t)b * D_);
    const float4* w4 = reinterpret_cast<const float4*>(Wd + (size_t)d * D_);
    float acc = 0.f;
#pragma unroll
    for (int p = 0; p < 4; ++p) {
        float4 h = h4[lane + p * 64], w = w4[lane + p * 64];
        acc += h.x * w.x + h.y * w.y + h.z * w.z + h.w * w.w;
    }
#pragma unroll
    for (int off = 32; off > 0; off >>= 1) acc += __shfl_xor(acc, off);
    if (lane == 0) dec[o] = acc;
}

// ---------------------------------------------------------------------------
// K0: fp32 -> bf16 (RNE) bulk convert, 4 elements/thread
// ---------------------------------------------------------------------------
__device__ __forceinline__ uint16_t f2bf(float f) {
    uint32_t u = __float_as_uint(f);
    u += 0x7FFFu + ((u >> 16) & 1u);
    return (uint16_t)(u >> 16);
}

__global__ __launch_bounds__(256) void f32_to_bf16_kernel(
    const float* __restrict__ in, uint16_t* __restrict__ out, int n4)
{
    int i = blockIdx.x * 256 + threadIdx.x;
    if (i >= n4) return;
    float4 v = reinterpret_cast<const float4*>(in)[i];
    ushort4 o;
    o.x = f2bf(v.x); o.y = f2bf(v.y); o.z = f2bf(v.z); o.w = f2bf(v.w);
    reinterpret_cast<ushort4*>(out)[i] = o;
}

// ---------------------------------------------------------------------------
// K2: MFMA bf16 GEMM fused with tanh + v-dot -> scores_t [B][S]
// 128x128 tile, BK=32, 4 waves x (4x4) mfma_f32_16x16x32_bf16,
// global_load_lds width-16 staging. Epilogue uses fast_tanh.
// ---------------------------------------------------------------------------
constexpr int TM = 128, TN = 128, TK = 32;

__global__ __launch_bounds__(256) void score_mfma_kernel(
    const uint16_t* __restrict__ A,   // enc bf16 [M, K]
    const uint16_t* __restrict__ Bw,  // We  bf16 [D, K]
    const float* __restrict__ dec,    // [B, D]
    const float* __restrict__ v,      // [D]
    float* __restrict__ scores_t)     // [B, S], pre-zeroed, atomic accumulate
{
    __shared__ __align__(16) uint16_t As[TM * TK];  // 8 KB
    __shared__ __align__(16) uint16_t Bs[TN * TK];  // 8 KB

    const int nb = blockIdx.x & 7;
    const int mb = blockIdx.x >> 3;
    const int m0 = mb * TM;
    const int n0 = nb * TN;

    const int t    = threadIdx.x;
    const int wave = t >> 6;
    const int lane = t & 63;
    const int wm   = (wave & 1) * 64;
    const int wn   = (wave >> 1) * 64;
    const int q    = lane >> 4;
    const int r16  = lane & 15;

    const int srow = lane >> 2;
    const int scol = (lane & 3) * 8;

    f32x4 acc[4][4] = {};

    for (int k0 = 0; k0 < K_; k0 += TK) {
        __syncthreads();
#pragma unroll
        for (int i = 0; i < 2; ++i) {
            const int c = wave * 2 + i;
            const uint16_t* ga = A + (size_t)(m0 + c * 16 + srow) * K_ + k0 + scol;
            __builtin_amdgcn_global_load_lds(
                (const __attribute__((address_space(1))) uint32_t*)ga,
                (__attribute__((address_space(3))) uint32_t*)(As + c * 512),
                16, 0, 0);
            const uint16_t* gb = Bw + (size_t)(n0 + c * 16 + srow) * K_ + k0 + scol;
            __builtin_amdgcn_global_load_lds(
                (const __attribute__((address_space(1))) uint32_t*)gb,
                (__attribute__((address_space(3))) uint32_t*)(Bs + c * 512),
                16, 0, 0);
        }
        __syncthreads();

        bf16x8 af[4], bf[4];
#pragma unroll
        for (int i = 0; i < 4; ++i) {
            af[i] = __builtin_bit_cast(bf16x8,
                *reinterpret_cast<const int4*>(As + (wm + i * 16 + r16) * TK + q * 8));
            bf[i] = __builtin_bit_cast(bf16x8,
                *reinterpret_cast<const int4*>(Bs + (wn + i * 16 + r16) * TK + q * 8));
        }
#pragma unroll
        for (int i = 0; i < 4; ++i)
#pragma unroll
            for (int j = 0; j < 4; ++j)
                acc[i][j] = __builtin_amdgcn_mfma_f32_16x16x32_bf16(
                    af[i], bf[j], acc[i][j], 0, 0, 0);
    }

    // v[n] for this thread's 4 columns (hoisted, L2-cached)
    float vj[4];
#pragma unroll
    for (int j = 0; j < 4; ++j) vj[j] = v[n0 + wn + j * 16 + r16];

    // epilogue: C/D layout col = lane&15, row = q*4 + reg
#pragma unroll
    for (int i = 0; i < 4; ++i) {
#pragma unroll
        for (int r = 0; r < 4; ++r) {
            const int m = m0 + wm + i * 16 + q * 4 + r;
            const int b = m & (B_ - 1);
            float p = 0.f;
#pragma unroll
            for (int j = 0; j < 4; ++j) {
                const int n = n0 + wn + j * 16 + r16;
                p += vj[j] * fast_tanh(acc[i][j][r] + dec[b * D_ + n]);
            }
            p += __shfl_xor(p, 1);
            p += __shfl_xor(p, 2);
            p += __shfl_xor(p, 4);
            p += __shfl_xor(p, 8);
            if (r16 == 0) atomicAdd(&scores_t[b * S_ + (m >> 5)], p);
        }
    }
}

// ---------------------------------------------------------------------------
// K3: softmax over s per batch, coalesced [B][S] layout
// ---------------------------------------------------------------------------
__global__ __launch_bounds__(256) void softmax_t_kernel(
    const float* __restrict__ scores_t,  // [B, S]
    float* __restrict__ attn)            // [B, S]
{
    const int b = blockIdx.x;
    const int t = threadIdx.x;
    __shared__ float sm[256];

    const float4* sp = reinterpret_cast<const float4*>(scores_t + (size_t)b * S_);
    float4 v0 = sp[t], v1 = sp[t + 256];

    float lmax = fmaxf(fmaxf(fmaxf(v0.x, v0.y), fmaxf(v0.z, v0.w)),
                       fmaxf(fmaxf(v1.x, v1.y), fmaxf(v1.z, v1.w)));
    sm[t] = lmax; __syncthreads();
    for (int off = 128; off > 0; off >>= 1) {
        if (t < off) sm[t] = fmaxf(sm[t], sm[t + off]);
        __syncthreads();
    }
    const float mx = sm[0];
    __syncthreads();

    v0.x = __builtin_amdgcn_exp2f((v0.x - mx) * 1.44269504f);
    v0.y = __builtin_amdgcn_exp2f((v0.y - mx) * 1.44269504f);
    v0.z = __builtin_amdgcn_exp2f((v0.z - mx) * 1.44269504f);
    v0.w = __builtin_amdgcn_exp2f((v0.w - mx) * 1.44269504f);
    v1.x = __builtin_amdgcn_exp2f((v1.x - mx) * 1.44269504f);
    v1.y = __builtin_amdgcn_exp2f((v1.y - mx) * 1.44269504f);
    v1.z = __builtin_amdgcn_exp2f((v1.z - mx) * 1.44269504f);
    v1.w = __builtin_amdgcn_exp2f((v1.w - mx) * 1.44269504f);

    float lsum = v0.x + v0.y + v0.z + v0.w + v1.x + v1.y + v1.z + v1.w;
    sm[t] = lsum; __syncthreads();
    for (int off = 128; off > 0; off >>= 1) {
        if (t < off) sm[t] += sm[t + off];
        __syncthreads();
    }
    const float inv = 1.f / sm[0];
    float4* op = reinterpret_cast<float4*>(attn + (size_t)b * S_);
    v0.x *= inv; v0.y *= inv; v0.z *= inv; v0.w *= inv;
    v1.x *= inv; v1.y *= inv; v1.z *= inv; v1.w *= inv;
    op[t] = v0; op[t + 256] = v1;
}

// ---------------------------------------------------------------------------
// K4a: context partials: part[sc][b][e] = sum_{s in chunk} attn[b,s]*enc[s,b,e]
// grid = SC_*B_ = 1024 blocks; no atomics.
// ---------------------------------------------------------------------------
__global__ __launch_bounds__(256) void context_part_kernel(
    const uint16_t* __restrict__ encb,  // [S, B, E] bf16
    const float* __restrict__ attn,     // [B, S]
    float* __restrict__ part)           // [SC_, B, E]
{
    const int b  = blockIdx.x & (B_ - 1);
    const int sc = blockIdx.x >> 5;
    const int e0 = threadIdx.x * 4;
    constexpr int SLEN = S_ / SC_;      // 64

    float a0 = 0.f, a1 = 0.f, a2 = 0.f, a3 = 0.f;
    const int s0 = sc * SLEN;
#pragma unroll 2
    for (int s = s0; s < s0 + SLEN; ++s) {
        const float w = attn[b * S_ + s];
        uint2 u = *reinterpret_cast<const uint2*>(
            encb + ((size_t)s * B_ + b) * E_ + e0);
        a0 += w * __uint_as_float((u.x & 0xFFFFu) << 16);
        a1 += w * __uint_as_float(u.x & 0xFFFF0000u);
        a2 += w * __uint_as_float((u.y & 0xFFFFu) << 16);
        a3 += w * __uint_as_float(u.y & 0xFFFF0000u);
    }
    float4 o = {a0, a1, a2, a3};
    *reinterpret_cast<float4*>(part + ((size_t)sc * B_ + b) * E_ + e0) = o;
}

// K4b: ctx[b,e] = sum_sc part[sc][b][e]
__global__ __launch_bounds__(256) void context_reduce_kernel(
    const float* __restrict__ part, float* __restrict__ ctx)
{
    const int i = blockIdx.x * 256 + threadIdx.x;  // b*E + e
    float acc = 0.f;
#pragma unroll
    for (int sc = 0; sc < SC_; ++sc) acc += part[(size_t)sc * B_ * E_ + i];
    ctx[i] = acc;
}

// ---------------------------------------------------------------------------
// Fallback fp32 path (ws too small): round-1 kernels
// ---------------------------------------------------------------------------
constexpr int BM = 64, BN = 64, BK = 16;

__global__ __launch_bounds__(256) void score_gemm_kernel(
    const float* __restrict__ enc, const float* __restrict__ We,
    const float* __restrict__ dec, const float* __restrict__ v,
    float* __restrict__ scores)
{
    __shared__ float As[BM][BK + 1];
    __shared__ float Bs[BN][BK + 1];
    __shared__ float red[BM][17];
    const int m0 = blockIdx.x * BM;
    const int n0 = blockIdx.y * BN;
    const int t  = threadIdx.x;
    const int tx = t & 15;
    const int ty = t >> 4;
    const int lrow = t >> 2;
    const int lcol = (t & 3) * 4;
    float acc[4][4] = {};
    for (int k0 = 0; k0 < E_; k0 += BK) {
        float4 a = *reinterpret_cast<const float4*>(enc + (size_t)(m0 + lrow) * E_ + k0 + lcol);
        float4 w = *reinterpret_cast<const float4*>(We + (size_t)(n0 + lrow) * E_ + k0 + lcol);
        As[lrow][lcol + 0] = a.x; As[lrow][lcol + 1] = a.y;
        As[lrow][lcol + 2] = a.z; As[lrow][lcol + 3] = a.w;
        Bs[lrow][lcol + 0] = w.x; Bs[lrow][lcol + 1] = w.y;
        Bs[lrow][lcol + 2] = w.z; Bs[lrow][lcol + 3] = w.w;
        __syncthreads();
#pragma unroll
        for (int kk = 0; kk < BK; ++kk) {
            float av[4], bw[4];
#pragma unroll
            for (int i = 0; i < 4; ++i) av[i] = As[ty * 4 + i][kk];
#pragma unroll
            for (int j = 0; j < 4; ++j) bw[j] = Bs[tx * 4 + j][kk];
#pragma unroll
            for (int i = 0; i < 4; ++i)
#pragma unroll
                for (int j = 0; j < 4; ++j)
                    acc[i][j] += av[i] * bw[j];
        }
        __syncthreads();
    }
    float p[4];
#pragma unroll
    for (int i = 0; i < 4; ++i) {
        int m = m0 + ty * 4 + i;
        int b = m & (B_ - 1);
        float s = 0.f;
#pragma unroll
        for (int j = 0; j < 4; ++j) {
            int n = n0 + tx * 4 + j;
            s += v[n] * tanhf(acc[i][j] + dec[b * D_ + n]);
        }
        p[i] = s;
    }
#pragma unroll
    for (int i = 0; i < 4; ++i) red[ty * 4 + i][tx] = p[i];
    __syncthreads();
    if (t < BM) {
        float s = 0.f;
#pragma unroll
        for (int j = 0; j < 16; ++j) s += red[t][j];
        atomicAdd(&scores[m0 + t], s);
    }
}

__global__ __launch_bounds__(256) void softmax_kernel(
    const float* __restrict__ scores, float* __restrict__ attn)
{
    const int b = blockIdx.x;
    const int t = threadIdx.x;
    __shared__ float sm[256];
    float vals[8];
    float lmax = -INFINITY;
#pragma unroll
    for (int i = 0; i < 8; ++i) {
        int s = t + i * 256;
        vals[i] = scores[s * B_ + b];
        lmax = fmaxf(lmax, vals[i]);
    }
    sm[t] = lmax; __syncthreads();
    for (int off = 128; off > 0; off >>= 1) {
        if (t < off) sm[t] = fmaxf(sm[t], sm[t + off]);
        __syncthreads();
    }
    const float mx = sm[0];
    __syncthreads();
    float lsum = 0.f;
#pragma unroll
    for (int i = 0; i < 8; ++i) {
        vals[i] = expf(vals[i] - mx);
        lsum += vals[i];
    }
    sm[t] = lsum; __syncthreads();
    for (int off = 128; off > 0; off >>= 1) {
        if (t < off) sm[t] += sm[t + off];
        __syncthreads();
    }
    const float inv = 1.f / sm[0];
#pragma unroll
    for (int i = 0; i < 8; ++i)
        attn[b * S_ + t + i * 256] = vals[i] * inv;
}

__global__ __launch_bounds__(256) void context_kernel(
    const float* __restrict__ enc, const float* __restrict__ attn,
    float* __restrict__ ctx)
{
    const int e0 = (blockIdx.x & 3) * 256;
    const int b  = (blockIdx.x >> 2) & (B_ - 1);
    const int sc = blockIdx.x >> 7;
    const int e  = e0 + threadIdx.x;
    float acc = 0.f;
    const int s_end = sc * 256 + 256;
    for (int s = sc * 256; s < s_end; ++s)
        acc += attn[b * S_ + s] * enc[((size_t)s * B_ + b) * E_ + e];
    atomicAdd(&ctx[b * E_ + e], acc);
}

// ---------------------------------------------------------------------------
extern "C" void kernel_launch(void* const* d_in, const int* in_sizes, int n_in,
                              void* d_out, int out_size, void* d_ws, size_t ws_size,
                              hipStream_t stream) {
    const float* hidden = (const float*)d_in[0];  // [B, D]
    const float* enc    = (const float*)d_in[1];  // [S, B, E]
    const float* We     = (const float*)d_in[2];  // [D, E]
    const float* Wd     = (const float*)d_in[3];  // [D, D]
    const float* v      = (const float*)d_in[4];  // [D]

    float* ctx  = (float*)d_out;                  // [B, E]
    float* attn = (float*)d_out + B_ * E_;        // [B, S]

    float*    dec    = (float*)d_ws;              // [B*D]
    float*    scores = dec + B_ * D_;             // [M]  (scores_t in fast path)
    uint16_t* Web    = (uint16_t*)(scores + M_);  // [D*K]
    uint16_t* encb   = Web + (size_t)D_ * K_;     // [M*K]
    float*    part   = (float*)(encb + (size_t)M_ * K_);  // [SC_*B*E]

    const size_t need = (size_t)(B_ * D_ + M_) * 4
                      + ((size_t)D_ * K_ + (size_t)M_ * K_) * 2
                      + (size_t)SC_ * B_ * E_ * 4;
    const bool fast = ws_size >= need;

    hipMemsetAsync(scores, 0, (size_t)M_ * sizeof(float), stream);

    dec_proj_wave_kernel<<<(B_ * D_) / 4, 256, 0, stream>>>(hidden, Wd, dec);

    if (fast) {
        f32_to_bf16_kernel<<<(D_ * K_ / 4) / 256, 256, 0, stream>>>(
            We, Web, D_ * K_ / 4);
        const int enc_n4 = M_ * K_ / 4;
        f32_to_bf16_kernel<<<enc_n4 / 256, 256, 0, stream>>>(enc, encb, enc_n4);

        score_mfma_kernel<<<(M_ / TM) * (D_ / TN), 256, 0, stream>>>(
            encb, Web, dec, v, scores);

        softmax_t_kernel<<<B_, 256, 0, stream>>>(scores, attn);
        context_part_kernel<<<SC_ * B_, 256, 0, stream>>>(encb, attn, part);
        context_reduce_kernel<<<(B_ * E_) / 256, 256, 0, stream>>>(part, ctx);
    } else {
        hipMemsetAsync(ctx, 0, (size_t)B_ * E_ * sizeof(float), stream);
        dim3 g2(M_ / BM, D_ / BN);
        score_gemm_kernel<<<g2, 256, 0, stream>>>(enc, We, dec, v, scores);
        softmax_kernel<<<B_, 256, 0, stream>>>(scores, attn);
        context_kernel<<<B_ * 4 * 8, 256, 0, stream>>>(enc, attn, ctx);
    }
}

// Round 4
// 600.189 us; speedup vs baseline: 5.1353x; 1.1513x over previous
//
#include <hip/hip_runtime.h>
#include <cmath>
#include <cstdint>

// Problem constants: B=32, S=2048, E=1024, D=1024
constexpr int B_ = 32;
constexpr int S_ = 2048;
constexpr int E_ = 1024;
constexpr int D_ = 1024;
constexpr int K_ = E_;        // GEMM K
constexpr int M_ = S_ * B_;   // 65536 rows (m = s*B + b)
constexpr int SC_ = 32;       // context s-chunks
constexpr int NP_ = 16;       // score partial planes (8 nb x 2 wn)

typedef float f32x4 __attribute__((ext_vector_type(4)));
typedef __bf16 bf16x8 __attribute__((ext_vector_type(8)));

// fast tanh: 1 - 2/(exp(2x)+1); saturates correctly; ~6 VALU ops
__device__ __forceinline__ float fast_tanh(float x) {
    float e = __builtin_amdgcn_exp2f(x * 2.88539008177793f);
    return 1.f - 2.f * __builtin_amdgcn_rcpf(e + 1.f);
}

__device__ __forceinline__ uint16_t f2bf(float f) {
    uint32_t u = __float_as_uint(f);
    u += 0x7FFFu + ((u >> 16) & 1u);
    return (uint16_t)(u >> 16);
}

// ---------------------------------------------------------------------------
// K0: merged fp32->bf16 convert for enc (64M elems) + We (1M elems).
// 8 elems/thread: 2 float4 loads -> 1 uint4 (16 B) store.
// ---------------------------------------------------------------------------
constexpr int ENC_N8 = M_ * K_ / 8;   // 8388608 threads for enc
constexpr int WE_N8  = D_ * K_ / 8;   // 131072 threads for We
constexpr int CVT_BLOCKS = (ENC_N8 + WE_N8) / 256;  // 33280

__global__ __launch_bounds__(256) void convert_kernel(
    const float* __restrict__ enc, uint16_t* __restrict__ encb,
    const float* __restrict__ We,  uint16_t* __restrict__ Web)
{
    int tid = blockIdx.x * 256 + threadIdx.x;
    const float* src;
    uint16_t* dst;
    int i8;
    if (tid < ENC_N8) { src = enc; dst = encb; i8 = tid; }
    else              { src = We;  dst = Web;  i8 = tid - ENC_N8; }
    const float4* s4 = reinterpret_cast<const float4*>(src) + i8 * 2;
    float4 a = s4[0], b = s4[1];
    uint4 o;
    o.x = (uint32_t)f2bf(a.x) | ((uint32_t)f2bf(a.y) << 16);
    o.y = (uint32_t)f2bf(a.z) | ((uint32_t)f2bf(a.w) << 16);
    o.z = (uint32_t)f2bf(b.x) | ((uint32_t)f2bf(b.y) << 16);
    o.w = (uint32_t)f2bf(b.z) | ((uint32_t)f2bf(b.w) << 16);
    reinterpret_cast<uint4*>(dst)[i8] = o;
}

// ---------------------------------------------------------------------------
// K1: dec_proj[b,d] = sum_k hidden[b,k]*Wd[d,k]. One wave per output.
// ---------------------------------------------------------------------------
__global__ __launch_bounds__(256) void dec_proj_wave_kernel(
    const float* __restrict__ hidden, const float* __restrict__ Wd,
    float* __restrict__ dec)
{
    const int o = blockIdx.x * 4 + (threadIdx.x >> 6);
    const int lane = threadIdx.x & 63;
    const int b = o >> 10;
    const int d = o & (D_ - 1);
    const float4* h4 = reinterpret_cast<const float4*>(hidden + (size_t)b * D_);
    const float4* w4 = reinterpret_cast<const float4*>(Wd + (size_t)d * D_);
    float acc = 0.f;
#pragma unroll
    for (int p = 0; p < 4; ++p) {
        float4 h = h4[lane + p * 64], w = w4[lane + p * 64];
        acc += h.x * w.x + h.y * w.y + h.z * w.z + h.w * w.w;
    }
#pragma unroll
    for (int off = 32; off > 0; off >>= 1) acc += __shfl_xor(acc, off);
    if (lane == 0) dec[o] = acc;
}

// ---------------------------------------------------------------------------
// K2: MFMA bf16 GEMM fused with tanh + v-dot -> 16 partial score planes.
// 128x128 tile, TK=64 as two 32-k sub-tiles (16 iters, half the barriers).
// XCD swizzle: the 8 n-blocks of an m-tile are consecutive slots on ONE XCD
// so the shared A-tile stays in that XCD's L2 (short vmcnt drains).
// No atomics: wave (nb, wn) writes plane p = nb*2 + wn/64.
// ---------------------------------------------------------------------------
constexpr int TM = 128, TN = 128;

__global__ __launch_bounds__(256) void score_mfma_kernel(
    const uint16_t* __restrict__ A,   // enc bf16 [M, K]
    const uint16_t* __restrict__ Bw,  // We  bf16 [D, K]
    const float* __restrict__ dec,    // [B, D]
    const float* __restrict__ v,      // [D]
    float* __restrict__ spart)        // [NP_, M_]  (m indexed as b*S + s)
{
    __shared__ __align__(16) uint16_t As[2][TM * 32];  // two 8 KB halves
    __shared__ __align__(16) uint16_t Bs[2][TN * 32];

    // XCD-aware decode: p%8 = XCD (round-robin heuristic)
    const int p    = blockIdx.x;
    const int xcd  = p & 7;
    const int slot = p >> 3;
    const int nb   = slot & 7;
    const int mb   = xcd + 8 * (slot >> 3);
    const int m0 = mb * TM;
    const int n0 = nb * TN;

    const int t    = threadIdx.x;
    const int wave = t >> 6;
    const int lane = t & 63;
    const int wm   = (wave & 1) * 64;
    const int wn   = (wave >> 1) * 64;
    const int q    = lane >> 4;
    const int r16  = lane & 15;

    const int srow = lane >> 2;        // 0..15 row within 16-row chunk
    const int scol = (lane & 3) * 8;   // u16 col offset (16 B granule)

    f32x4 acc[4][4] = {};

    for (int k0 = 0; k0 < K_; k0 += 64) {
        __syncthreads();
#pragma unroll
        for (int h = 0; h < 2; ++h) {
            const int kk = k0 + h * 32;
#pragma unroll
            for (int i = 0; i < 2; ++i) {
                const int c = wave * 2 + i;   // 16-row chunk 0..7
                const uint16_t* ga = A + (size_t)(m0 + c * 16 + srow) * K_ + kk + scol;
                __builtin_amdgcn_global_load_lds(
                    (const __attribute__((address_space(1))) uint32_t*)ga,
                    (__attribute__((address_space(3))) uint32_t*)(As[h] + c * 512),
                    16, 0, 0);
                const uint16_t* gb = Bw + (size_t)(n0 + c * 16 + srow) * K_ + kk + scol;
                __builtin_amdgcn_global_load_lds(
                    (const __attribute__((address_space(1))) uint32_t*)gb,
                    (__attribute__((address_space(3))) uint32_t*)(Bs[h] + c * 512),
                    16, 0, 0);
            }
        }
        __syncthreads();

#pragma unroll
        for (int h = 0; h < 2; ++h) {
            bf16x8 af[4], bf[4];
#pragma unroll
            for (int i = 0; i < 4; ++i) {
                af[i] = __builtin_bit_cast(bf16x8,
                    *reinterpret_cast<const int4*>(As[h] + (wm + i * 16 + r16) * 32 + q * 8));
                bf[i] = __builtin_bit_cast(bf16x8,
                    *reinterpret_cast<const int4*>(Bs[h] + (wn + i * 16 + r16) * 32 + q * 8));
            }
#pragma unroll
            for (int i = 0; i < 4; ++i)
#pragma unroll
                for (int j = 0; j < 4; ++j)
                    acc[i][j] = __builtin_amdgcn_mfma_f32_16x16x32_bf16(
                        af[i], bf[j], acc[i][j], 0, 0, 0);
        }
    }

    float vj[4];
#pragma unroll
    for (int j = 0; j < 4; ++j) vj[j] = v[n0 + wn + j * 16 + r16];

    float* plane = spart + (size_t)(nb * 2 + (wn >> 6)) * M_;

    // epilogue: C/D layout col = lane&15, row = q*4 + reg
#pragma unroll
    for (int i = 0; i < 4; ++i) {
#pragma unroll
        for (int r = 0; r < 4; ++r) {
            const int m = m0 + wm + i * 16 + q * 4 + r;
            const int b = m & (B_ - 1);
            float pv = 0.f;
#pragma unroll
            for (int j = 0; j < 4; ++j) {
                const int n = n0 + wn + j * 16 + r16;
                pv += vj[j] * fast_tanh(acc[i][j][r] + dec[b * D_ + n]);
            }
            pv += __shfl_xor(pv, 1);
            pv += __shfl_xor(pv, 2);
            pv += __shfl_xor(pv, 4);
            pv += __shfl_xor(pv, 8);
            if (r16 == 0) plane[b * S_ + (m >> 5)] = pv;
        }
    }
}

// ---------------------------------------------------------------------------
// K3: softmax over s per batch; sums the 16 partial planes first.
// ---------------------------------------------------------------------------
__global__ __launch_bounds__(256) void softmax16_kernel(
    const float* __restrict__ spart,  // [NP_, M_], plane rows are [b][s]
    float* __restrict__ attn)         // [B, S]
{
    const int b = blockIdx.x;
    const int t = threadIdx.x;
    __shared__ float sm[256];

    const float4* base = reinterpret_cast<const float4*>(spart + (size_t)b * S_);
    constexpr int PSTRIDE = M_ / 4;   // float4 stride between planes
    float4 v0 = {0, 0, 0, 0}, v1 = {0, 0, 0, 0};
#pragma unroll
    for (int p = 0; p < NP_; ++p) {
        float4 a = base[(size_t)p * PSTRIDE + t];
        float4 c = base[(size_t)p * PSTRIDE + t + 256];
        v0.x += a.x; v0.y += a.y; v0.z += a.z; v0.w += a.w;
        v1.x += c.x; v1.y += c.y; v1.z += c.z; v1.w += c.w;
    }

    float lmax = fmaxf(fmaxf(fmaxf(v0.x, v0.y), fmaxf(v0.z, v0.w)),
                       fmaxf(fmaxf(v1.x, v1.y), fmaxf(v1.z, v1.w)));
    sm[t] = lmax; __syncthreads();
    for (int off = 128; off > 0; off >>= 1) {
        if (t < off) sm[t] = fmaxf(sm[t], sm[t + off]);
        __syncthreads();
    }
    const float mx = sm[0];
    __syncthreads();

    v0.x = __builtin_amdgcn_exp2f((v0.x - mx) * 1.44269504f);
    v0.y = __builtin_amdgcn_exp2f((v0.y - mx) * 1.44269504f);
    v0.z = __builtin_amdgcn_exp2f((v0.z - mx) * 1.44269504f);
    v0.w = __builtin_amdgcn_exp2f((v0.w - mx) * 1.44269504f);
    v1.x = __builtin_amdgcn_exp2f((v1.x - mx) * 1.44269504f);
    v1.y = __builtin_amdgcn_exp2f((v1.y - mx) * 1.44269504f);
    v1.z = __builtin_amdgcn_exp2f((v1.z - mx) * 1.44269504f);
    v1.w = __builtin_amdgcn_exp2f((v1.w - mx) * 1.44269504f);

    float lsum = v0.x + v0.y + v0.z + v0.w + v1.x + v1.y + v1.z + v1.w;
    sm[t] = lsum; __syncthreads();
    for (int off = 128; off > 0; off >>= 1) {
        if (t < off) sm[t] += sm[t + off];
        __syncthreads();
    }
    const float inv = 1.f / sm[0];
    float4* op = reinterpret_cast<float4*>(attn + (size_t)b * S_);
    v0.x *= inv; v0.y *= inv; v0.z *= inv; v0.w *= inv;
    v1.x *= inv; v1.y *= inv; v1.z *= inv; v1.w *= inv;
    op[t] = v0; op[t + 256] = v1;
}

// ---------------------------------------------------------------------------
// K4a: context partials; K4b: reduce. part reuses the spart region (spart is
// dead after softmax; stream order guarantees no overlap hazard).
// ---------------------------------------------------------------------------
__global__ __launch_bounds__(256) void context_part_kernel(
    const uint16_t* __restrict__ encb, const float* __restrict__ attn,
    float* __restrict__ part)          // [SC_, B, E]
{
    const int b  = blockIdx.x & (B_ - 1);
    const int sc = blockIdx.x >> 5;
    const int e0 = threadIdx.x * 4;
    constexpr int SLEN = S_ / SC_;     // 64

    float a0 = 0.f, a1 = 0.f, a2 = 0.f, a3 = 0.f;
    const int s0 = sc * SLEN;
#pragma unroll 2
    for (int s = s0; s < s0 + SLEN; ++s) {
        const float w = attn[b * S_ + s];
        uint2 u = *reinterpret_cast<const uint2*>(
            encb + ((size_t)s * B_ + b) * E_ + e0);
        a0 += w * __uint_as_float((u.x & 0xFFFFu) << 16);
        a1 += w * __uint_as_float(u.x & 0xFFFF0000u);
        a2 += w * __uint_as_float((u.y & 0xFFFFu) << 16);
        a3 += w * __uint_as_float(u.y & 0xFFFF0000u);
    }
    float4 o = {a0, a1, a2, a3};
    *reinterpret_cast<float4*>(part + ((size_t)sc * B_ + b) * E_ + e0) = o;
}

__global__ __launch_bounds__(256) void context_reduce_kernel(
    const float* __restrict__ part, float* __restrict__ ctx)
{
    const int i = blockIdx.x * 256 + threadIdx.x;
    float acc = 0.f;
#pragma unroll
    for (int sc = 0; sc < SC_; ++sc) acc += part[(size_t)sc * B_ * E_ + i];
    ctx[i] = acc;
}

// ---------------------------------------------------------------------------
// Fallback fp32 path (ws too small)
// ---------------------------------------------------------------------------
constexpr int BM = 64, BN = 64, BK = 16;

__global__ __launch_bounds__(256) void score_gemm_kernel(
    const float* __restrict__ enc, const float* __restrict__ We,
    const float* __restrict__ dec, const float* __restrict__ v,
    float* __restrict__ scores)
{
    __shared__ float As[BM][BK + 1];
    __shared__ float Bs[BN][BK + 1];
    __shared__ float red[BM][17];
    const int m0 = blockIdx.x * BM;
    const int n0 = blockIdx.y * BN;
    const int t  = threadIdx.x;
    const int tx = t & 15;
    const int ty = t >> 4;
    const int lrow = t >> 2;
    const int lcol = (t & 3) * 4;
    float acc[4][4] = {};
    for (int k0 = 0; k0 < E_; k0 += BK) {
        float4 a = *reinterpret_cast<const float4*>(enc + (size_t)(m0 + lrow) * E_ + k0 + lcol);
        float4 w = *reinterpret_cast<const float4*>(We + (size_t)(n0 + lrow) * E_ + k0 + lcol);
        As[lrow][lcol + 0] = a.x; As[lrow][lcol + 1] = a.y;
        As[lrow][lcol + 2] = a.z; As[lrow][lcol + 3] = a.w;
        Bs[lrow][lcol + 0] = w.x; Bs[lrow][lcol + 1] = w.y;
        Bs[lrow][lcol + 2] = w.z; Bs[lrow][lcol + 3] = w.w;
        __syncthreads();
#pragma unroll
        for (int kk = 0; kk < BK; ++kk) {
            float av[4], bw[4];
#pragma unroll
            for (int i = 0; i < 4; ++i) av[i] = As[ty * 4 + i][kk];
#pragma unroll
            for (int j = 0; j < 4; ++j) bw[j] = Bs[tx * 4 + j][kk];
#pragma unroll
            for (int i = 0; i < 4; ++i)
#pragma unroll
                for (int j = 0; j < 4; ++j)
                    acc[i][j] += av[i] * bw[j];
        }
        __syncthreads();
    }
    float pp[4];
#pragma unroll
    for (int i = 0; i < 4; ++i) {
        int m = m0 + ty * 4 + i;
        int b = m & (B_ - 1);
        float s = 0.f;
#pragma unroll
        for (int j = 0; j < 4; ++j) {
            int n = n0 + tx * 4 + j;
            s += v[n] * tanhf(acc[i][j] + dec[b * D_ + n]);
        }
        pp[i] = s;
    }
#pragma unroll
    for (int i = 0; i < 4; ++i) red[ty * 4 + i][tx] = pp[i];
    __syncthreads();
    if (t < BM) {
        float s = 0.f;
#pragma unroll
        for (int j = 0; j < 16; ++j) s += red[t][j];
        atomicAdd(&scores[m0 + t], s);
    }
}

__global__ __launch_bounds__(256) void softmax_kernel(
    const float* __restrict__ scores, float* __restrict__ attn)
{
    const int b = blockIdx.x;
    const int t = threadIdx.x;
    __shared__ float sm[256];
    float vals[8];
    float lmax = -INFINITY;
#pragma unroll
    for (int i = 0; i < 8; ++i) {
        int s = t + i * 256;
        vals[i] = scores[s * B_ + b];
        lmax = fmaxf(lmax, vals[i]);
    }
    sm[t] = lmax; __syncthreads();
    for (int off = 128; off > 0; off >>= 1) {
        if (t < off) sm[t] = fmaxf(sm[t], sm[t + off]);
        __syncthreads();
    }
    const float mx = sm[0];
    __syncthreads();
    float lsum = 0.f;
#pragma unroll
    for (int i = 0; i < 8; ++i) {
        vals[i] = expf(vals[i] - mx);
        lsum += vals[i];
    }
    sm[t] = lsum; __syncthreads();
    for (int off = 128; off > 0; off >>= 1) {
        if (t < off) sm[t] += sm[t + off];
        __syncthreads();
    }
    const float inv = 1.f / sm[0];
#pragma unroll
    for (int i = 0; i < 8; ++i)
        attn[b * S_ + t + i * 256] = vals[i] * inv;
}

__global__ __launch_bounds__(256) void context_kernel(
    const float* __restrict__ enc, const float* __restrict__ attn,
    float* __restrict__ ctx)
{
    const int e0 = (blockIdx.x & 3) * 256;
    const int b  = (blockIdx.x >> 2) & (B_ - 1);
    const int sc = blockIdx.x >> 7;
    const int e  = e0 + threadIdx.x;
    float acc = 0.f;
    const int s_end = sc * 256 + 256;
    for (int s = sc * 256; s < s_end; ++s)
        acc += attn[b * S_ + s] * enc[((size_t)s * B_ + b) * E_ + e];
    atomicAdd(&ctx[b * E_ + e], acc);
}

// ---------------------------------------------------------------------------
extern "C" void kernel_launch(void* const* d_in, const int* in_sizes, int n_in,
                              void* d_out, int out_size, void* d_ws, size_t ws_size,
                              hipStream_t stream) {
    const float* hidden = (const float*)d_in[0];
    const float* enc    = (const float*)d_in[1];
    const float* We     = (const float*)d_in[2];
    const float* Wd     = (const float*)d_in[3];
    const float* v      = (const float*)d_in[4];

    float* ctx  = (float*)d_out;
    float* attn = (float*)d_out + B_ * E_;

    float*    dec   = (float*)d_ws;                  // [B*D]         128 KB
    float*    spart = dec + B_ * D_;                 // [NP_*M_]      4 MB (reused as ctx partials)
    uint16_t* Web   = (uint16_t*)(spart + (size_t)NP_ * M_);  // [D*K] 2 MB
    uint16_t* encb  = Web + (size_t)D_ * K_;         // [M*K]         128 MB

    const size_t need = (size_t)B_ * D_ * 4 + (size_t)NP_ * M_ * 4
                      + ((size_t)D_ * K_ + (size_t)M_ * K_) * 2;
    const bool fast = ws_size >= need;

    if (fast) {
        convert_kernel<<<CVT_BLOCKS, 256, 0, stream>>>(enc, encb, We, Web);
        dec_proj_wave_kernel<<<(B_ * D_) / 4, 256, 0, stream>>>(hidden, Wd, dec);

        score_mfma_kernel<<<(M_ / TM) * (D_ / TN), 256, 0, stream>>>(
            encb, Web, dec, v, spart);

        softmax16_kernel<<<B_, 256, 0, stream>>>(spart, attn);
        // spart region reused for context partials (dead after softmax)
        context_part_kernel<<<SC_ * B_, 256, 0, stream>>>(encb, attn, spart);
        context_reduce_kernel<<<(B_ * E_) / 256, 256, 0, stream>>>(spart, ctx);
    } else {
        float* scores = spart;  // [M] fits in the 4 MB region
        hipMemsetAsync(scores, 0, (size_t)M_ * sizeof(float), stream);
        hipMemsetAsync(ctx, 0, (size_t)B_ * E_ * sizeof(float), stream);
        dec_proj_wave_kernel<<<(B_ * D_) / 4, 256, 0, stream>>>(hidden, Wd, dec);
        dim3 g2(M_ / BM, D_ / BN);
        score_gemm_kernel<<<g2, 256, 0, stream>>>(enc, We, dec, v, scores);
        softmax_kernel<<<B_, 256, 0, stream>>>(scores, attn);
        context_kernel<<<B_ * 4 * 8, 256, 0, stream>>>(enc, attn, ctx);
    }
}

// Round 6
// 561.363 us; speedup vs baseline: 5.4904x; 1.0692x over previous
//
#include <hip/hip_runtime.h>
#include <cmath>
#include <cstdint>

// Problem constants: B=32, S=2048, E=1024, D=1024
constexpr int B_ = 32;
constexpr int S_ = 2048;
constexpr int E_ = 1024;
constexpr int D_ = 1024;
constexpr int K_ = E_;        // GEMM K
constexpr int M_ = S_ * B_;   // 65536 rows (m = s*B + b)
constexpr int SC_ = 32;       // context s-chunks
constexpr int NP_ = 16;       // score partial planes (8 nb x 2 wn)

typedef float f32x4 __attribute__((ext_vector_type(4)));
typedef float fvec4 __attribute__((ext_vector_type(4)));
typedef __bf16 bf16x8 __attribute__((ext_vector_type(8)));

// fast tanh: 1 - 2/(exp(2x)+1); saturates correctly; ~6 VALU ops
__device__ __forceinline__ float fast_tanh(float x) {
    float e = __builtin_amdgcn_exp2f(x * 2.88539008177793f);
    return 1.f - 2.f * __builtin_amdgcn_rcpf(e + 1.f);
}

__device__ __forceinline__ uint16_t f2bf(float f) {
    uint32_t u = __float_as_uint(f);
    u += 0x7FFFu + ((u >> 16) & 1u);
    return (uint16_t)(u >> 16);
}

// ---------------------------------------------------------------------------
// K0: fused prep: fp32->bf16 convert (enc, We) + dec_proj.
// ---------------------------------------------------------------------------
constexpr int ENC_N8 = M_ * K_ / 8;   // 8388608
constexpr int WE_N8  = D_ * K_ / 8;   // 131072
constexpr int CVT_BLOCKS = (ENC_N8 + WE_N8) / 256;  // 33280
constexpr int DEC_BLOCKS = (B_ * D_) / 4;           // 8192

__global__ __launch_bounds__(256) void prep_kernel(
    const float* __restrict__ enc, uint16_t* __restrict__ encb,
    const float* __restrict__ We,  uint16_t* __restrict__ Web,
    const float* __restrict__ hidden, const float* __restrict__ Wd,
    float* __restrict__ dec)
{
    const int bid = blockIdx.x;
    if (bid < CVT_BLOCKS) {
        int tid = bid * 256 + threadIdx.x;
        const float* src;
        uint16_t* dst;
        int i8;
        if (tid < ENC_N8) { src = enc; dst = encb; i8 = tid; }
        else              { src = We;  dst = Web;  i8 = tid - ENC_N8; }
        const fvec4* s4 = reinterpret_cast<const fvec4*>(src) + (size_t)i8 * 2;
        fvec4 a = __builtin_nontemporal_load(s4);
        fvec4 b = __builtin_nontemporal_load(s4 + 1);
        uint4 o;
        o.x = (uint32_t)f2bf(a.x) | ((uint32_t)f2bf(a.y) << 16);
        o.y = (uint32_t)f2bf(a.z) | ((uint32_t)f2bf(a.w) << 16);
        o.z = (uint32_t)f2bf(b.x) | ((uint32_t)f2bf(b.y) << 16);
        o.w = (uint32_t)f2bf(b.z) | ((uint32_t)f2bf(b.w) << 16);
        reinterpret_cast<uint4*>(dst)[i8] = o;
    } else {
        const int o = (bid - CVT_BLOCKS) * 4 + (threadIdx.x >> 6);
        const int lane = threadIdx.x & 63;
        const int b = o >> 10;
        const int d = o & (D_ - 1);
        const float4* h4 = reinterpret_cast<const float4*>(hidden + (size_t)b * D_);
        const float4* w4 = reinterpret_cast<const float4*>(Wd + (size_t)d * D_);
        float acc = 0.f;
#pragma unroll
        for (int p = 0; p < 4; ++p) {
            float4 h = h4[lane + p * 64], w = w4[lane + p * 64];
            acc += h.x * w.x + h.y * w.y + h.z * w.z + h.w * w.w;
        }
#pragma unroll
        for (int off = 32; off > 0; off >>= 1) acc += __shfl_xor(acc, off);
        if (lane == 0) dec[o] = acc;
    }
}

// ---------------------------------------------------------------------------
// K2: MFMA bf16 GEMM fused with tanh + v-dot -> 16 partial score planes.
// 128x128 tile, TK=64 (two 32-k halves), XCD-swizzled block order,
// pointer-increment staging (ALL global_load_lds use offset=0 — the offset
// immediate is NOT safe for global->LDS; learned round 5), register-preloaded
// dec/v for the epilogue.
// ---------------------------------------------------------------------------
constexpr int TM = 128, TN = 128;

__global__ __launch_bounds__(256) void score_mfma_kernel(
    const uint16_t* __restrict__ A,   // enc bf16 [M, K]
    const uint16_t* __restrict__ Bw,  // We  bf16 [D, K]
    const float* __restrict__ dec,    // [B, D]
    const float* __restrict__ v,      // [D]
    float* __restrict__ spart)        // [NP_, M_]  (rows are b*S + s)
{
    __shared__ __align__(16) uint16_t As[2][TM * 32];  // two 8 KB halves
    __shared__ __align__(16) uint16_t Bs[2][TN * 32];

    // XCD-aware decode: the 8 n-blocks of one m-tile sit on one XCD
    const int p    = blockIdx.x;
    const int xcd  = p & 7;
    const int slot = p >> 3;
    const int nb   = slot & 7;
    const int mb   = xcd + 8 * (slot >> 3);
    const int m0 = mb * TM;
    const int n0 = nb * TN;

    const int t    = threadIdx.x;
    const int wave = t >> 6;
    const int lane = t & 63;
    const int wm   = (wave & 1) * 64;
    const int wn   = (wave >> 1) * 64;
    const int q    = lane >> 4;
    const int r16  = lane & 15;

    const int srow = lane >> 2;        // row within 16-row chunk
    const int scol = (lane & 3) * 8;   // u16 col offset (16 B granule)

    // 8 staging pointers (one per destination), all advanced 64 elems/iter
    const int c0 = wave * 2, c1 = wave * 2 + 1;
    const uint16_t* ga00 = A + (size_t)(m0 + c0 * 16 + srow) * K_ + scol;       // h=0
    const uint16_t* ga01 = ga00 + 32;                                           // h=1
    const uint16_t* ga10 = A + (size_t)(m0 + c1 * 16 + srow) * K_ + scol;
    const uint16_t* ga11 = ga10 + 32;
    const uint16_t* gb00 = Bw + (size_t)(n0 + c0 * 16 + srow) * K_ + scol;
    const uint16_t* gb01 = gb00 + 32;
    const uint16_t* gb10 = Bw + (size_t)(n0 + c1 * 16 + srow) * K_ + scol;
    const uint16_t* gb11 = gb10 + 32;
    typedef __attribute__((address_space(3))) uint32_t lds_u32;
    typedef const __attribute__((address_space(1))) uint32_t g_u32;
    lds_u32* dA00 = (lds_u32*)(As[0] + c0 * 512);
    lds_u32* dA01 = (lds_u32*)(As[1] + c0 * 512);
    lds_u32* dA10 = (lds_u32*)(As[0] + c1 * 512);
    lds_u32* dA11 = (lds_u32*)(As[1] + c1 * 512);
    lds_u32* dB00 = (lds_u32*)(Bs[0] + c0 * 512);
    lds_u32* dB01 = (lds_u32*)(Bs[1] + c0 * 512);
    lds_u32* dB10 = (lds_u32*)(Bs[0] + c1 * 512);
    lds_u32* dB11 = (lds_u32*)(Bs[1] + c1 * 512);

    // preload epilogue constants: v columns + the 32 unique dec values
    float vj[4];
#pragma unroll
    for (int j = 0; j < 4; ++j) vj[j] = v[n0 + wn + j * 16 + r16];
    float dec_r[2][4][4];   // [i&1][r][j]; b = (i&1)*16 + q*4 + r
#pragma unroll
    for (int i01 = 0; i01 < 2; ++i01)
#pragma unroll
        for (int r = 0; r < 4; ++r) {
            const int b = i01 * 16 + q * 4 + r;
#pragma unroll
            for (int j = 0; j < 4; ++j)
                dec_r[i01][r][j] = dec[b * D_ + n0 + wn + j * 16 + r16];
        }

    f32x4 acc[4][4] = {};

    for (int it = 0; it < K_ / 64; ++it) {
        __syncthreads();
        __builtin_amdgcn_global_load_lds((g_u32*)ga00, dA00, 16, 0, 0);
        __builtin_amdgcn_global_load_lds((g_u32*)ga01, dA01, 16, 0, 0);
        __builtin_amdgcn_global_load_lds((g_u32*)ga10, dA10, 16, 0, 0);
        __builtin_amdgcn_global_load_lds((g_u32*)ga11, dA11, 16, 0, 0);
        __builtin_amdgcn_global_load_lds((g_u32*)gb00, dB00, 16, 0, 0);
        __builtin_amdgcn_global_load_lds((g_u32*)gb01, dB01, 16, 0, 0);
        __builtin_amdgcn_global_load_lds((g_u32*)gb10, dB10, 16, 0, 0);
        __builtin_amdgcn_global_load_lds((g_u32*)gb11, dB11, 16, 0, 0);
        ga00 += 64; ga01 += 64; ga10 += 64; ga11 += 64;
        gb00 += 64; gb01 += 64; gb10 += 64; gb11 += 64;
        __syncthreads();

#pragma unroll
        for (int h = 0; h < 2; ++h) {
            bf16x8 af[4], bf[4];
#pragma unroll
            for (int i = 0; i < 4; ++i) {
                af[i] = __builtin_bit_cast(bf16x8,
                    *reinterpret_cast<const int4*>(As[h] + (wm + i * 16 + r16) * 32 + q * 8));
                bf[i] = __builtin_bit_cast(bf16x8,
                    *reinterpret_cast<const int4*>(Bs[h] + (wn + i * 16 + r16) * 32 + q * 8));
            }
#pragma unroll
            for (int i = 0; i < 4; ++i)
#pragma unroll
                for (int j = 0; j < 4; ++j)
                    acc[i][j] = __builtin_amdgcn_mfma_f32_16x16x32_bf16(
                        af[i], bf[j], acc[i][j], 0, 0, 0);
        }
    }

    float* plane = spart + (size_t)(nb * 2 + (wn >> 6)) * M_;

    // epilogue: C/D layout col = lane&15, row = q*4 + reg
#pragma unroll
    for (int i = 0; i < 4; ++i) {
#pragma unroll
        for (int r = 0; r < 4; ++r) {
            const int m = m0 + wm + i * 16 + q * 4 + r;
            const int b = (i & 1) * 16 + q * 4 + r;
            float pv = 0.f;
#pragma unroll
            for (int j = 0; j < 4; ++j)
                pv += vj[j] * fast_tanh(acc[i][j][r] + dec_r[i & 1][r][j]);
            pv += __shfl_xor(pv, 1);
            pv += __shfl_xor(pv, 2);
            pv += __shfl_xor(pv, 4);
            pv += __shfl_xor(pv, 8);
            if (r16 == 0) plane[b * S_ + (m >> 5)] = pv;
        }
    }
}

// ---------------------------------------------------------------------------
// K3: softmax over s per batch; sums the 16 partial planes first.
// ---------------------------------------------------------------------------
__global__ __launch_bounds__(256) void softmax16_kernel(
    const float* __restrict__ spart,  // [NP_, M_], plane rows are [b][s]
    float* __restrict__ attn)         // [B, S]
{
    const int b = blockIdx.x;
    const int t = threadIdx.x;
    __shared__ float sm[256];

    const float4* base = reinterpret_cast<const float4*>(spart + (size_t)b * S_);
    constexpr int PSTRIDE = M_ / 4;
    float4 v0 = {0, 0, 0, 0}, v1 = {0, 0, 0, 0};
#pragma unroll
    for (int p = 0; p < NP_; ++p) {
        float4 a = base[(size_t)p * PSTRIDE + t];
        float4 c = base[(size_t)p * PSTRIDE + t + 256];
        v0.x += a.x; v0.y += a.y; v0.z += a.z; v0.w += a.w;
        v1.x += c.x; v1.y += c.y; v1.z += c.z; v1.w += c.w;
    }

    float lmax = fmaxf(fmaxf(fmaxf(v0.x, v0.y), fmaxf(v0.z, v0.w)),
                       fmaxf(fmaxf(v1.x, v1.y), fmaxf(v1.z, v1.w)));
    sm[t] = lmax; __syncthreads();
    for (int off = 128; off > 0; off >>= 1) {
        if (t < off) sm[t] = fmaxf(sm[t], sm[t + off]);
        __syncthreads();
    }
    const float mx = sm[0];
    __syncthreads();

    v0.x = __builtin_amdgcn_exp2f((v0.x - mx) * 1.44269504f);
    v0.y = __builtin_amdgcn_exp2f((v0.y - mx) * 1.44269504f);
    v0.z = __builtin_amdgcn_exp2f((v0.z - mx) * 1.44269504f);
    v0.w = __builtin_amdgcn_exp2f((v0.w - mx) * 1.44269504f);
    v1.x = __builtin_amdgcn_exp2f((v1.x - mx) * 1.44269504f);
    v1.y = __builtin_amdgcn_exp2f((v1.y - mx) * 1.44269504f);
    v1.z = __builtin_amdgcn_exp2f((v1.z - mx) * 1.44269504f);
    v1.w = __builtin_amdgcn_exp2f((v1.w - mx) * 1.44269504f);

    float lsum = v0.x + v0.y + v0.z + v0.w + v1.x + v1.y + v1.z + v1.w;
    sm[t] = lsum; __syncthreads();
    for (int off = 128; off > 0; off >>= 1) {
        if (t < off) sm[t] += sm[t + off];
        __syncthreads();
    }
    const float inv = 1.f / sm[0];
    float4* op = reinterpret_cast<float4*>(attn + (size_t)b * S_);
    v0.x *= inv; v0.y *= inv; v0.z *= inv; v0.w *= inv;
    v1.x *= inv; v1.y *= inv; v1.z *= inv; v1.w *= inv;
    op[t] = v0; op[t + 256] = v1;
}

// ---------------------------------------------------------------------------
// K4a: context partials (reuses spart region); K4b: reduce.
// ---------------------------------------------------------------------------
__global__ __launch_bounds__(256) void context_part_kernel(
    const uint16_t* __restrict__ encb, const float* __restrict__ attn,
    float* __restrict__ part)          // [SC_, B, E]
{
    const int b  = blockIdx.x & (B_ - 1);
    const int sc = blockIdx.x >> 5;
    const int e0 = threadIdx.x * 4;
    constexpr int SLEN = S_ / SC_;     // 64

    float a0 = 0.f, a1 = 0.f, a2 = 0.f, a3 = 0.f;
    const int s0 = sc * SLEN;
#pragma unroll 2
    for (int s = s0; s < s0 + SLEN; ++s) {
        const float w = attn[b * S_ + s];
        uint2 u = *reinterpret_cast<const uint2*>(
            encb + ((size_t)s * B_ + b) * E_ + e0);
        a0 += w * __uint_as_float((u.x & 0xFFFFu) << 16);
        a1 += w * __uint_as_float(u.x & 0xFFFF0000u);
        a2 += w * __uint_as_float((u.y & 0xFFFFu) << 16);
        a3 += w * __uint_as_float(u.y & 0xFFFF0000u);
    }
    float4 o = {a0, a1, a2, a3};
    *reinterpret_cast<float4*>(part + ((size_t)sc * B_ + b) * E_ + e0) = o;
}

__global__ __launch_bounds__(256) void context_reduce_kernel(
    const float* __restrict__ part, float* __restrict__ ctx)
{
    const int i = blockIdx.x * 256 + threadIdx.x;
    float acc = 0.f;
#pragma unroll
    for (int sc = 0; sc < SC_; ++sc) acc += part[(size_t)sc * B_ * E_ + i];
    ctx[i] = acc;
}

// ---------------------------------------------------------------------------
// Fallback fp32 path (ws too small)
// ---------------------------------------------------------------------------
constexpr int BM = 64, BN = 64, BK = 16;

__global__ __launch_bounds__(256) void dec_proj_wave_kernel(
    const float* __restrict__ hidden, const float* __restrict__ Wd,
    float* __restrict__ dec)
{
    const int o = blockIdx.x * 4 + (threadIdx.x >> 6);
    const int lane = threadIdx.x & 63;
    const int b = o >> 10;
    const int d = o & (D_ - 1);
    const float4* h4 = reinterpret_cast<const float4*>(hidden + (size_t)b * D_);
    const float4* w4 = reinterpret_cast<const float4*>(Wd + (size_t)d * D_);
    float acc = 0.f;
#pragma unroll
    for (int p = 0; p < 4; ++p) {
        float4 h = h4[lane + p * 64], w = w4[lane + p * 64];
        acc += h.x * w.x + h.y * w.y + h.z * w.z + h.w * w.w;
    }
#pragma unroll
    for (int off = 32; off > 0; off >>= 1) acc += __shfl_xor(acc, off);
    if (lane == 0) dec[o] = acc;
}

__global__ __launch_bounds__(256) void score_gemm_kernel(
    const float* __restrict__ enc, const float* __restrict__ We,
    const float* __restrict__ dec, const float* __restrict__ v,
    float* __restrict__ scores)
{
    __shared__ float As[BM][BK + 1];
    __shared__ float Bs[BN][BK + 1];
    __shared__ float red[BM][17];
    const int m0 = blockIdx.x * BM;
    const int n0 = blockIdx.y * BN;
    const int t  = threadIdx.x;
    const int tx = t & 15;
    const int ty = t >> 4;
    const int lrow = t >> 2;
    const int lcol = (t & 3) * 4;
    float acc[4][4] = {};
    for (int k0 = 0; k0 < E_; k0 += BK) {
        float4 a = *reinterpret_cast<const float4*>(enc + (size_t)(m0 + lrow) * E_ + k0 + lcol);
        float4 w = *reinterpret_cast<const float4*>(We + (size_t)(n0 + lrow) * E_ + k0 + lcol);
        As[lrow][lcol + 0] = a.x; As[lrow][lcol + 1] = a.y;
        As[lrow][lcol + 2] = a.z; As[lrow][lcol + 3] = a.w;
        Bs[lrow][lcol + 0] = w.x; Bs[lrow][lcol + 1] = w.y;
        Bs[lrow][lcol + 2] = w.z; Bs[lrow][lcol + 3] = w.w;
        __syncthreads();
#pragma unroll
        for (int kk = 0; kk < BK; ++kk) {
            float av[4], bw[4];
#pragma unroll
            for (int i = 0; i < 4; ++i) av[i] = As[ty * 4 + i][kk];
#pragma unroll
            for (int j = 0; j < 4; ++j) bw[j] = Bs[tx * 4 + j][kk];
#pragma unroll
            for (int i = 0; i < 4; ++i)
#pragma unroll
                for (int j = 0; j < 4; ++j)
                    acc[i][j] += av[i] * bw[j];
        }
        __syncthreads();
    }
    float pp[4];
#pragma unroll
    for (int i = 0; i < 4; ++i) {
        int m = m0 + ty * 4 + i;
        int b = m & (B_ - 1);
        float s = 0.f;
#pragma unroll
        for (int j = 0; j < 4; ++j) {
            int n = n0 + tx * 4 + j;
            s += v[n] * tanhf(acc[i][j] + dec[b * D_ + n]);
        }
        pp[i] = s;
    }
#pragma unroll
    for (int i = 0; i < 4; ++i) red[ty * 4 + i][tx] = pp[i];
    __syncthreads();
    if (t < BM) {
        float s = 0.f;
#pragma unroll
        for (int j = 0; j < 16; ++j) s += red[t][j];
        atomicAdd(&scores[m0 + t], s);
    }
}

__global__ __launch_bounds__(256) void softmax_kernel(
    const float* __restrict__ scores, float* __restrict__ attn)
{
    const int b = blockIdx.x;
    const int t = threadIdx.x;
    __shared__ float sm[256];
    float vals[8];
    float lmax = -INFINITY;
#pragma unroll
    for (int i = 0; i < 8; ++i) {
        int s = t + i * 256;
        vals[i] = scores[s * B_ + b];
        lmax = fmaxf(lmax, vals[i]);
    }
    sm[t] = lmax; __syncthreads();
    for (int off = 128; off > 0; off >>= 1) {
        if (t < off) sm[t] = fmaxf(sm[t], sm[t + off]);
        __syncthreads();
    }
    const float mx = sm[0];
    __syncthreads();
    float lsum = 0.f;
#pragma unroll
    for (int i = 0; i < 8; ++i) {
        vals[i] = expf(vals[i] - mx);
        lsum += vals[i];
    }
    sm[t] = lsum; __syncthreads();
    for (int off = 128; off > 0; off >>= 1) {
        if (t < off) sm[t] += sm[t + off];
        __syncthreads();
    }
    const float inv = 1.f / sm[0];
#pragma unroll
    for (int i = 0; i < 8; ++i)
        attn[b * S_ + t + i * 256] = vals[i] * inv;
}

__global__ __launch_bounds__(256) void context_kernel(
    const float* __restrict__ enc, const float* __restrict__ attn,
    float* __restrict__ ctx)
{
    const int e0 = (blockIdx.x & 3) * 256;
    const int b  = (blockIdx.x >> 2) & (B_ - 1);
    const int sc = blockIdx.x >> 7;
    const int e  = e0 + threadIdx.x;
    float acc = 0.f;
    const int s_end = sc * 256 + 256;
    for (int s = sc * 256; s < s_end; ++s)
        acc += attn[b * S_ + s] * enc[((size_t)s * B_ + b) * E_ + e];
    atomicAdd(&ctx[b * E_ + e], acc);
}

// ---------------------------------------------------------------------------
extern "C" void kernel_launch(void* const* d_in, const int* in_sizes, int n_in,
                              void* d_out, int out_size, void* d_ws, size_t ws_size,
                              hipStream_t stream) {
    const float* hidden = (const float*)d_in[0];
    const float* enc    = (const float*)d_in[1];
    const float* We     = (const float*)d_in[2];
    const float* Wd     = (const float*)d_in[3];
    const float* v      = (const float*)d_in[4];

    float* ctx  = (float*)d_out;
    float* attn = (float*)d_out + B_ * E_;

    float*    dec   = (float*)d_ws;                  // [B*D]
    float*    spart = dec + B_ * D_;                 // [NP_*M_] (reused as ctx partials)
    uint16_t* Web   = (uint16_t*)(spart + (size_t)NP_ * M_);  // [D*K]
    uint16_t* encb  = Web + (size_t)D_ * K_;         // [M*K]

    const size_t need = (size_t)B_ * D_ * 4 + (size_t)NP_ * M_ * 4
                      + ((size_t)D_ * K_ + (size_t)M_ * K_) * 2;
    const bool fast = ws_size >= need;

    if (fast) {
        prep_kernel<<<CVT_BLOCKS + DEC_BLOCKS, 256, 0, stream>>>(
            enc, encb, We, Web, hidden, Wd, dec);

        score_mfma_kernel<<<(M_ / TM) * (D_ / TN), 256, 0, stream>>>(
            encb, Web, dec, v, spart);

        softmax16_kernel<<<B_, 256, 0, stream>>>(spart, attn);
        context_part_kernel<<<SC_ * B_, 256, 0, stream>>>(encb, attn, spart);
        context_reduce_kernel<<<(B_ * E_) / 256, 256, 0, stream>>>(spart, ctx);
    } else {
        float* scores = spart;
        hipMemsetAsync(scores, 0, (size_t)M_ * sizeof(float), stream);
        hipMemsetAsync(ctx, 0, (size_t)B_ * E_ * sizeof(float), stream);
        dec_proj_wave_kernel<<<(B_ * D_) / 4, 256, 0, stream>>>(hidden, Wd, dec);
        dim3 g2(M_ / BM, D_ / BN);
        score_gemm_kernel<<<g2, 256, 0, stream>>>(enc, We, dec, v, scores);
        softmax_kernel<<<B_, 256, 0, stream>>>(scores, attn);
        context_kernel<<<B_ * 4 * 8, 256, 0, stream>>>(enc, attn, ctx);
    }
}